// Round 2
// baseline (21226.413 us; speedup 1.0000x reference)
//
#include <hip/hip_runtime.h>
#include <hip/hip_bf16.h>
#include <cstdint>
#include <cstddef>

// ============================================================================
// BiSLSTM (B=32, S=1024, E=256, H=256, K=2), fp32 in/out.  Round 4.
//
// R3 post-mortem: replicated-s architecture is right but the implementation
// leaked: 16-way LDS conflicts on scalar s-frag writes (24M conflicts),
// all-256-thread flag polling (MALL line ping-pong), oversized c/rsx gather.
// R4 fixes, same architecture:
//   * P4 GEMM TRANSPOSED: mfma(wbig, hf) -> D[j,b]; thread owns 4 consecutive
//     j -> one packed ds_write_b64 per (Mt,n) (~4-way), float4 c/rsx gather.
//   * h-frags gathered DIRECTLY into VGPRs (lane loads its own MFMA fragment
//     from Hbuf) -> no LDS h staging, P1/P4/rsh all read h from registers.
//   * wave0-only poll; flags spread one per 64B line; s_sleep(2) backoff.
//   * rsx exchanged in f32 (more accurate, simple float4 gather).
//   * barriers/step: S1, S2, S3a(poll release), S4.
// ============================================================================

typedef __bf16 bf16x8 __attribute__((ext_vector_type(8)));
typedef float  f32x4  __attribute__((ext_vector_type(4)));
typedef unsigned long long u64x2 __attribute__((ext_vector_type(2)));

#define DEVINL __device__ __forceinline__

constexpr int Ss = 1024;

// ---- ws layout (bytes) ----
constexpr size_t OFF_FLAGS = 0;                    // 4 KB: flag (d,g) at (d*32+g)*64
constexpr size_t OFF_H   = 4096;                   // [2 pc][2 d][32 b][256 u] bf16
constexpr size_t SZ_H    = (size_t)2*2*32*256*2;   // 65536
constexpr size_t OFF_R   = OFF_H + SZ_H;           // [2 pc][2 d][32 b][256 j] f32
constexpr size_t SZ_RC   = (size_t)2*2*32*256*4;   // 131072
constexpr size_t OFF_C   = OFF_R + SZ_RC;          // [2 pc][2 d][32 b][256 j] f32
constexpr size_t OFF_WH  = OFF_C + SZ_RC;          // [2][1024 col][256 k] bf16
constexpr size_t SZ_W    = (size_t)2*1024*256*2;   // 1 MB
constexpr size_t OFF_WX  = OFF_WH + SZ_W;
constexpr size_t OFF_WS  = OFF_WX + SZ_W;
constexpr size_t OFF_WRX = OFF_WS + SZ_W;          // [2][2*256 j][256 k] bf16
constexpr size_t SZ_WR   = (size_t)2*2*256*256*2;  // 512 KB
constexpr size_t OFF_WRH = OFF_WRX + SZ_WR;        // end ~4.32 MB

DEVINL unsigned short f2bf(float f) {                 // RNE fp32->bf16
    unsigned u = __builtin_bit_cast(unsigned, f);
    u += 0x7FFFu + ((u >> 16) & 1u);
    return (unsigned short)(u >> 16);
}
DEVINL unsigned long long pack4(float4 v) {
    return (unsigned long long)f2bf(v.x) | ((unsigned long long)f2bf(v.y) << 16)
         | ((unsigned long long)f2bf(v.z) << 32) | ((unsigned long long)f2bf(v.w) << 48);
}
DEVINL float sigm(float x) { return 1.f / (1.f + __expf(-x)); }

DEVINL unsigned long long ald64(const unsigned long long* p) {
    return __hip_atomic_load(p, __ATOMIC_RELAXED, __HIP_MEMORY_SCOPE_AGENT);
}
DEVINL unsigned ald32(const unsigned* p) {
    return __hip_atomic_load(p, __ATOMIC_RELAXED, __HIP_MEMORY_SCOPE_AGENT);
}
DEVINL void ast32u(unsigned* p, unsigned v) {
    __hip_atomic_store(p, v, __ATOMIC_RELAXED, __HIP_MEMORY_SCOPE_AGENT);
}
DEVINL void ast32f(float* p, float v) {
    __hip_atomic_store(p, v, __ATOMIC_RELAXED, __HIP_MEMORY_SCOPE_AGENT);
}
DEVINL void ast16(unsigned short* p, unsigned short v) {
    __hip_atomic_store(p, v, __ATOMIC_RELAXED, __HIP_MEMORY_SCOPE_AGENT);
}

// ---------------------------------------------------------------------------
__global__ void prepass(const float* __restrict__ Wx0, const float* __restrict__ Wh0,
                        const float* __restrict__ Ws0,
                        const float* __restrict__ Wx1, const float* __restrict__ Wh1,
                        const float* __restrict__ Ws1,
                        const float* __restrict__ Wrx0, const float* __restrict__ Wrh0,
                        const float* __restrict__ Wrx1, const float* __restrict__ Wrh1,
                        unsigned char* __restrict__ ws)
{
    unsigned short* whT  = (unsigned short*)(ws + OFF_WH);
    unsigned short* wxT  = (unsigned short*)(ws + OFF_WX);
    unsigned short* wsT  = (unsigned short*)(ws + OFF_WS);
    unsigned short* wrxT = (unsigned short*)(ws + OFF_WRX);
    unsigned short* wrhT = (unsigned short*)(ws + OFF_WRH);
    int tid = blockIdx.x * blockDim.x + threadIdx.x;
    int NT  = gridDim.x * blockDim.x;
    // [d][n][k] = W[k*1024+n]
    for (int e = tid; e < 2*1024*256; e += NT) {
        int d = e >> 18, r = e & 262143, n = r >> 8, k = r & 255;
        whT[e] = f2bf((d ? Wh1 : Wh0)[k*1024 + n]);
        wxT[e] = f2bf((d ? Wx1 : Wx0)[k*1024 + n]);
        wsT[e] = f2bf((d ? Ws1 : Ws0)[k*1024 + n]);
    }
    // [d][kk*256+j][k] = W[(kk*256+k)*256+j]
    for (int e = tid; e < 2*2*256*256; e += NT) {
        int d = e >> 17, r = e & 131071, kk = r >> 16, r2 = r & 65535;
        int j = r2 >> 8, k = r2 & 255;
        wrxT[e] = f2bf((d ? Wrx1 : Wrx0)[(kk*256 + k)*256 + j]);
        wrhT[e] = f2bf((d ? Wrh1 : Wrh0)[(kk*256 + k)*256 + j]);
    }
    // zero flag region (4 KB; ws poisoned each launch)
    if (blockIdx.x == 0 && threadIdx.x < 256) {
        unsigned* f = (unsigned*)ws;
#pragma unroll
        for (int i = 0; i < 4; ++i) f[threadIdx.x*4 + i] = 0u;
    }
}

// ---------------------------------------------------------------------------
// sA: s-only A-fragments [2 Mt][8 kt][4 lq][16 m] x 16B = 16 KB.
__launch_bounds__(256, 1)
__global__ void bislstm(const float* __restrict__ inputs, const float* __restrict__ mask,
                        const float* __restrict__ b0,  const float* __restrict__ b1,
                        const float* __restrict__ br0, const float* __restrict__ br1,
                        const int* __restrict__ idxp,
                        unsigned char* __restrict__ ws, float* __restrict__ out)
{
    const int bid = blockIdx.x;
    const int d   = bid >> 5;          // direction
    const int g   = bid & 31;          // unit group (units 8g..8g+7)
    const int tid = threadIdx.x;
    const int wave = tid >> 6, lane = tid & 63;
    const int lm = lane & 15, lq = lane >> 4;

    __shared__ __align__(16) unsigned short sA[8192];   // 16 KB s frags
    __shared__ float zs[2][32][16];
    __shared__ float rsxS[2][32][16];                   // parity dbuf, both shares, own cols
    __shared__ float rshS[32][16];
    __shared__ float mL[32];

    const unsigned short* whT  = (const unsigned short*)(ws + OFF_WH)  + (size_t)d*1024*256;
    const unsigned short* wxT  = (const unsigned short*)(ws + OFF_WX)  + (size_t)d*1024*256;
    const unsigned short* wsT  = (const unsigned short*)(ws + OFF_WS)  + (size_t)d*1024*256;
    const unsigned short* wrxT = (const unsigned short*)(ws + OFF_WRX) + (size_t)d*2*256*256;
    const unsigned short* wrhT = (const unsigned short*)(ws + OFF_WRH) + (size_t)d*2*256*256;
    unsigned short* HbufS = (unsigned short*)(ws + OFF_H);
    float*          RbufF = (float*)(ws + OFF_R);
    float*          CbufF = (float*)(ws + OFF_C);
    unsigned* flags = (unsigned*)ws + d*512;            // flag g at +g*16 dwords (64B apart)
    const int idxv = idxp[0];
    const float* bd  = d ? b1  : b0;
    const float* brd = d ? br1 : br0;

    // z roles
    const int zMt = wave & 1, zNt = wave >> 1;
    const int znl = zNt*16 + lm;
    const int zcol = (znl >> 3)*256 + g*8 + (znl & 7);  // global z-column
    const int rks = lm >> 3;
    const int rj  = g*8 + (lm & 7);

    // ---- preload weight B-fragments ----
    // waves 0,1: rwf = Wrh slice (rsh for output share); waves 2,3: rwf = Wrx slice (rsx)
    bf16x8 whf[8], wsf[8], wxf[8], rwf[8], wbig[4][8];
#pragma unroll
    for (int kt = 0; kt < 8; ++kt) {
        whf[kt] = *(const bf16x8*)(whT + (size_t)zcol*256 + kt*32 + lq*8);
        wsf[kt] = *(const bf16x8*)(wsT + (size_t)zcol*256 + kt*32 + lq*8);
        wxf[kt] = *(const bf16x8*)(wxT + (size_t)zcol*256 + kt*32 + lq*8);
    }
    {
        const unsigned short* wrT = (wave < 2) ? wrhT : wrxT;
#pragma unroll
        for (int kt = 0; kt < 8; ++kt)
            rwf[kt] = *(const bf16x8*)(wrT + (size_t)(rks*256 + rj)*256 + kt*32 + lq*8);
    }
    // full Wrh[idx] as A-operand for the transposed r GEMM: lane lm = row j16
    float brj[16];
#pragma unroll
    for (int n = 0; n < 4; ++n) {
        const int j16 = wave*64 + n*16 + lm;
#pragma unroll
        for (int kt = 0; kt < 8; ++kt)
            wbig[n][kt] = *(const bf16x8*)(wrhT + (size_t)(idxv*256 + j16)*256 + kt*32 + lq*8);
#pragma unroll
        for (int r = 0; r < 4; ++r)
            brj[n*4 + r] = brd[idxv*256 + wave*64 + n*16 + lq*4 + r];
    }

    // ---- zero sA (s_{-1}=0) and h-frags (h_{-1}=0) ----
    bf16x8 hf[2][8];
    {
        unsigned long long* z8 = (unsigned long long*)sA;
#pragma unroll
        for (int i = 0; i < 8; ++i) z8[tid + 256*i] = 0ULL;
        u64x2 zz; zz.x = 0ULL; zz.y = 0ULL;
#pragma unroll
        for (int Mt = 0; Mt < 2; ++Mt)
#pragma unroll
        for (int kt = 0; kt < 8; ++kt) hf[Mt][kt] = __builtin_bit_cast(bf16x8, zz);
    }

    // ---- prologue: x_0 -> zacc (x@Wx partial) + rsx_0 (waves>=2) ----
    f32x4 zacc;
    {
        const int tx0 = d ? (Ss - 1) : 0;
        const float* xp = inputs + (((size_t)(zMt*16 + lm)*Ss + tx0) << 8) + lq*8;
        bf16x8 xf[8];
#pragma unroll
        for (int kt = 0; kt < 8; ++kt) {
            float4 v0 = *(const float4*)(xp + kt*32);
            float4 v1 = *(const float4*)(xp + kt*32 + 4);
            u64x2 pk; pk.x = pack4(v0); pk.y = pack4(v1);
            xf[kt] = __builtin_bit_cast(bf16x8, pk);
        }
        f32x4 a = {0.f, 0.f, 0.f, 0.f};
#pragma unroll
        for (int kt = 0; kt < 8; ++kt)
            a = __builtin_amdgcn_mfma_f32_16x16x32_bf16(xf[kt], wxf[kt], a, 0, 0, 0);
        zacc = a;
        if (wave >= 2) {
            f32x4 ra = {0.f, 0.f, 0.f, 0.f};
#pragma unroll
            for (int kt = 0; kt < 8; ++kt)
                ra = __builtin_amdgcn_mfma_f32_16x16x32_bf16(xf[kt], rwf[kt], ra, 0, 0, 0);
#pragma unroll
            for (int r = 0; r < 4; ++r) rsxS[0][zMt*16 + lq*4 + r][lm] = ra[r];
            if (rks == idxv) {
                float* Rf = RbufF + (size_t)d*8192;
#pragma unroll
                for (int r = 0; r < 4; ++r)
                    ast32f(Rf + (size_t)(zMt*16 + lq*4 + r)*256 + rj, ra[r]);
            }
        }
    }
    __syncthreads();

    // per-thread elementwise cell constants + state
    const int eb = tid >> 3, ej = tid & 7;
    const int gj = g*8 + ej;
    const float bias_i = bd[gj], bias_f = bd[256+gj], bias_g = bd[512+gj], bias_o = bd[768+gj];
    const float brr0 = brd[gj], brr1 = brd[256+gj];
    float hprev = 0.f, cprev = 0.f, s1prev = 0.f;
    float sreg[2][4][4] = {};                     // replicated s[idx] (j = wave*64+n*16+lq*4+r, b = Mt*16+lm)
    unsigned long long cg[2][4][2], rg[2][4][2];  // gathered c / rsx (f32 pairs)

    const unsigned short* aBase = sA + (size_t)(zMt*4096 + lq*128 + lm*8);

#pragma unroll 1
    for (int t = 0; t < Ss; ++t) {
        const int tx = d ? (Ss - 1 - t) : t;
        const int pc = t & 1, pcn = pc ^ 1;
        const unsigned want = (unsigned)(t + 1);
        const bool more = (t + 1 < Ss);

        // ---- P1: z = (x@Wx precomputed) + h@Wh (regs) + s@Ws (LDS frags) ----
        if (tid < 32) mL[tid] = mask[(size_t)tid*Ss + tx];
        {
            f32x4 acc = zacc;
#pragma unroll
            for (int kt = 0; kt < 8; ++kt)
                acc = __builtin_amdgcn_mfma_f32_16x16x32_bf16(hf[zMt][kt], whf[kt], acc, 0, 0, 0);
#pragma unroll
            for (int kt = 0; kt < 8; ++kt)
                acc = __builtin_amdgcn_mfma_f32_16x16x32_bf16(*(const bf16x8*)(aBase + kt*512), wsf[kt], acc, 0, 0, 0);
#pragma unroll
            for (int r = 0; r < 4; ++r)
                zs[zNt][zMt*16 + lq*4 + r][lm] = acc[r];
        }
        __syncthreads();                                   // S1

        // ---- P2: gates -> c,h ; publish h (bf16) + c (f32), [b][j] layouts ----
        float m_, cu_, hu_;
        {
            float zi = zs[0][eb][ej]   + bias_i;
            float zf = zs[0][eb][8+ej] + bias_f;
            float zg = zs[1][eb][ej]   + bias_g;
            float zo = zs[1][eb][8+ej] + bias_o;
            float cn = sigm(zf)*cprev + sigm(zi)*tanhf(zg);
            float hn = sigm(zo)*tanhf(cn);
            m_  = mL[eb];
            cu_ = m_*cn + (1.f - m_)*cprev;
            hu_ = m_*hn + (1.f - m_)*hprev;
            cprev = cu_; hprev = hu_;
            ast16(HbufS + (size_t)(pc*2 + d)*8192 + (size_t)eb*256 + gj, f2bf(hu_));
            ast32f(CbufF + (size_t)(pc*2 + d)*8192 + (size_t)eb*256 + gj, cu_);
        }
        asm volatile("s_waitcnt vmcnt(0)" ::: "memory");   // payload (+ last step's Rbuf) ack'd
        __syncthreads();                                   // S2

        // ---- P3: flag ; out h/c ; wave0-only poll ----
        if (tid == 0) ast32u(flags + g*16, want);
        out[((size_t)tx*32 + eb)*512 + d*256 + gj] = hu_;
        out[16777216 + ((size_t)tx*32 + eb)*512 + d*256 + gj] = cu_;
        if (wave == 0) {
            for (;;) {
                unsigned v = ald32(flags + (lane & 31)*16);
                if (__ballot(v < want) == 0ULL) break;
                __builtin_amdgcn_s_sleep(2);
            }
            asm volatile("" ::: "memory");
        }
        __syncthreads();                                   // S3a (poll release)

        // ---- P4pre: gather h-frags into regs + c/rsx float4s; overlap x MFMAs ----
        {
            const unsigned long long* Hs = (const unsigned long long*)(ws + OFF_H) + (size_t)(pc*2 + d)*2048;
#pragma unroll
            for (int Mt = 0; Mt < 2; ++Mt)
#pragma unroll
            for (int kt = 0; kt < 8; ++kt) {
                size_t u = (size_t)(Mt*16 + lm)*64 + kt*8 + lq*2;
                u64x2 pk; pk.x = ald64(Hs + u); pk.y = ald64(Hs + u + 1);
                hf[Mt][kt] = __builtin_bit_cast(bf16x8, pk);
            }
            const unsigned long long* Cb = (const unsigned long long*)(ws + OFF_C) + (size_t)(pc*2 + d)*4096;
            const unsigned long long* Rb = (const unsigned long long*)(ws + OFF_R) + (size_t)(pc*2 + d)*4096;
#pragma unroll
            for (int Mt = 0; Mt < 2; ++Mt)
#pragma unroll
            for (int n = 0; n < 4; ++n) {
                size_t fi = (size_t)(Mt*16 + lm)*128 + (unsigned)((wave*64 + n*16 + lq*4) >> 1);
                cg[Mt][n][0] = ald64(Cb + fi); cg[Mt][n][1] = ald64(Cb + fi + 1);
                rg[Mt][n][0] = ald64(Rb + fi); rg[Mt][n][1] = ald64(Rb + fi + 1);
            }
        }
        if (more) {
            const int txn = d ? (Ss - 2 - t) : (t + 1);
            const float* xp = inputs + (((size_t)(zMt*16 + lm)*Ss + txn) << 8) + lq*8;
            bf16x8 xf[8];
#pragma unroll
            for (int kt = 0; kt < 8; ++kt) {
                float4 v0 = *(const float4*)(xp + kt*32);
                float4 v1 = *(const float4*)(xp + kt*32 + 4);
                u64x2 pk; pk.x = pack4(v0); pk.y = pack4(v1);
                xf[kt] = __builtin_bit_cast(bf16x8, pk);
            }
            f32x4 a = {0.f, 0.f, 0.f, 0.f};
#pragma unroll
            for (int kt = 0; kt < 8; ++kt)
                a = __builtin_amdgcn_mfma_f32_16x16x32_bf16(xf[kt], wxf[kt], a, 0, 0, 0);
            zacc = a;
            if (wave >= 2) {       // rsx for step t+1 (x-only)
                f32x4 ra = {0.f, 0.f, 0.f, 0.f};
#pragma unroll
                for (int kt = 0; kt < 8; ++kt)
                    ra = __builtin_amdgcn_mfma_f32_16x16x32_bf16(xf[kt], rwf[kt], ra, 0, 0, 0);
#pragma unroll
                for (int r = 0; r < 4; ++r) rsxS[pcn][zMt*16 + lq*4 + r][lm] = ra[r];
                if (rks == idxv) {
                    float* Rf = RbufF + (size_t)(pcn*2 + d)*8192;
#pragma unroll
                    for (int r = 0; r < 4; ++r)
                        ast32f(Rf + (size_t)(zMt*16 + lq*4 + r)*256 + rj, ra[r]);
                }
            }
        }
        // rsh (h_t @ Wrh own cols, both shares) for P5 — h from regs
        if (wave < 2) {
            f32x4 ra = {0.f, 0.f, 0.f, 0.f};
#pragma unroll
            for (int kt = 0; kt < 8; ++kt)
                ra = __builtin_amdgcn_mfma_f32_16x16x32_bf16(hf[wave][kt], rwf[kt], ra, 0, 0, 0);
#pragma unroll
            for (int r = 0; r < 4; ++r) rshS[wave*16 + lq*4 + r][lm] = ra[r];
        }

        // ---- P4: transposed replicated r[idx] GEMM: D[j,b] = (Wrh^T)(h^T) ----
        {
            const float mvv[2] = { mL[lm], mL[16 + lm] };
#pragma unroll
            for (int Mt = 0; Mt < 2; ++Mt) {
#pragma unroll
                for (int n = 0; n < 4; ++n) {
                    f32x4 a = {0.f, 0.f, 0.f, 0.f};
#pragma unroll
                    for (int kt = 0; kt < 8; ++kt)
                        a = __builtin_amdgcn_mfma_f32_16x16x32_bf16(wbig[n][kt], hf[Mt][kt], a, 0, 0, 0);
                    const int j0 = wave*64 + n*16 + lq*4;
                    unsigned long long pk = 0ULL;
#pragma unroll
                    for (int r = 0; r < 4; ++r) {
                        float cv = __builtin_bit_cast(float, (unsigned)(cg[Mt][n][r >> 1] >> ((r & 1)*32)));
                        float rx = __builtin_bit_cast(float, (unsigned)(rg[Mt][n][r >> 1] >> ((r & 1)*32)));
                        float rr = sigm(a[r] + rx + brj[n*4 + r]);
                        float so = sreg[Mt][n][r];
                        float sn = rr*so + (1.f - rr)*cv;
                        float su = mvv[Mt]*sn + (1.f - mvv[Mt])*so;
                        sreg[Mt][n][r] = su;
                        pk |= (unsigned long long)f2bf(su) << (r*16);
                        if (((j0 + r) >> 3) == g)
                            out[33554432 + (((size_t)idxv*1024 + tx)*32 + (Mt*16 + lm))*512 + d*256 + (j0 + r)] = su;
                    }
                    const int ktp = wave*2 + (n >> 1);
                    const int lqv = (n & 1)*2 + (lq >> 1);
                    *(unsigned long long*)(sA + (size_t)(Mt*4096 + ktp*512 + lqv*128 + lm*8 + (lq & 1)*4)) = pk;
                }
            }
        }
        __syncthreads();                                   // S4

        // ---- P5: output-only share (1-idx), owner units, fp32-local ----
        {
            const int k1 = 1 - idxv;
            float rv = rsxS[pc][eb][k1*8 + ej] + rshS[eb][k1*8 + ej] + (k1 ? brr1 : brr0);
            float rr = sigm(rv);
            float sn = rr*s1prev + (1.f - rr)*cu_;
            float su = m_*sn + (1.f - m_)*s1prev;
            s1prev = su;
            out[33554432 + (((size_t)k1*1024 + tx)*32 + eb)*512 + d*256 + gj] = su;
        }
        // next conflicting LDS writes are behind S1/S3a of t+1
    }
}

// ---------------------------------------------------------------------------
extern "C" void kernel_launch(void* const* d_in, const int* in_sizes, int n_in,
                              void* d_out, int out_size, void* d_ws, size_t ws_size,
                              hipStream_t stream) {
    const float* inputs = (const float*)d_in[0];
    const float* mask_  = (const float*)d_in[1];
    const float* Wx0  = (const float*)d_in[2];
    const float* Wh0  = (const float*)d_in[3];
    const float* Ws0  = (const float*)d_in[4];
    const float* b0   = (const float*)d_in[5];
    const float* Wrx0 = (const float*)d_in[6];
    const float* Wrh0 = (const float*)d_in[7];
    const float* br0  = (const float*)d_in[8];
    const float* Wx1  = (const float*)d_in[9];
    const float* Wh1  = (const float*)d_in[10];
    const float* Ws1  = (const float*)d_in[11];
    const float* b1   = (const float*)d_in[12];
    const float* Wrx1 = (const float*)d_in[13];
    const float* Wrh1 = (const float*)d_in[14];
    const float* br1  = (const float*)d_in[15];
    const int*   idxp = (const int*)d_in[16];
    unsigned char* ws = (unsigned char*)d_ws;

    hipLaunchKernelGGL(prepass, dim3(512), dim3(256), 0, stream,
                       Wx0, Wh0, Ws0, Wx1, Wh1, Ws1, Wrx0, Wrh0, Wrx1, Wrh1, ws);
    hipLaunchKernelGGL(bislstm, dim3(64), dim3(256), 0, stream,
                       inputs, mask_, b0, b1, br0, br1, idxp,
                       ws, (float*)d_out);
}

// Round 3
// 13461.780 us; speedup vs baseline: 1.5768x; 1.5768x over previous
//
#include <hip/hip_runtime.h>
#include <hip/hip_bf16.h>
#include <cstdint>
#include <cstddef>

// ============================================================================
// BiSLSTM (B=32, S=1024, E=256, H=256, K=2), fp32 in/out.  Round 5.
//
// ONE device exchange per step (h bf16 + c f32 + rsx[idx] bf16); s[idx]
// recurrence replicated per block (bit-identical inputs -> identical bits).
// R3/R4 regressions traced to scattered sc1 accesses, NOT bank conflicts
// (15.7M conflicts = 240 cy/step — noise).  R5 uses R2-proven mechanics:
//   * publish: LDS-relay pack -> coalesced 8B device stores by waves 0/1
//   * gather:  coalesced u64/u64x2 loads -> LDS staging (h frags R2-style;
//     c/rsx padded row-major), epilogue reads contiguous float4/u64 from LDS
//   * wave0-only poll, 64B-spread flags; out stores after flag (lean ack)
//   * poll window: x-prefetch + zacc + rsx MFMAs
// Barriers/step: 6.  P4 transposed GEMM math identical to R4 (verified).
// ============================================================================

typedef __bf16 bf16x8 __attribute__((ext_vector_type(8)));
typedef float  f32x4  __attribute__((ext_vector_type(4)));
typedef unsigned long long u64x2 __attribute__((ext_vector_type(2)));
typedef unsigned long long u64;

#define DEVINL __device__ __forceinline__

constexpr int Ss = 1024;

constexpr size_t OFF_FLAGS = 0;                    // 4 KB
constexpr size_t OFF_H   = 4096;                   // [2pc][2d][32b][256u] bf16
constexpr size_t SZ_H    = (size_t)2*2*32*256*2;   // 64 KB
constexpr size_t OFF_C   = OFF_H + SZ_H;           // [2pc][2d][32b][256j] f32
constexpr size_t SZ_C    = (size_t)2*2*32*256*4;   // 128 KB
constexpr size_t OFF_R   = OFF_C + SZ_C;           // [2pc][2d][32b][256j] bf16
constexpr size_t SZ_R    = (size_t)2*2*32*256*2;   // 64 KB
constexpr size_t OFF_WH  = OFF_R + SZ_R;
constexpr size_t SZ_W    = (size_t)2*1024*256*2;   // 1 MB
constexpr size_t OFF_WX  = OFF_WH + SZ_W;
constexpr size_t OFF_WS  = OFF_WX + SZ_W;
constexpr size_t OFF_WRX = OFF_WS + SZ_W;
constexpr size_t SZ_WR   = (size_t)2*2*256*256*2;  // 512 KB
constexpr size_t OFF_WRH = OFF_WRX + SZ_WR;

DEVINL unsigned short f2bf(float f) {
    unsigned u = __builtin_bit_cast(unsigned, f);
    u += 0x7FFFu + ((u >> 16) & 1u);
    return (unsigned short)(u >> 16);
}
DEVINL u64 pack4(float4 v) {
    return (u64)f2bf(v.x) | ((u64)f2bf(v.y) << 16)
         | ((u64)f2bf(v.z) << 32) | ((u64)f2bf(v.w) << 48);
}
DEVINL float sigm(float x) { return 1.f / (1.f + __expf(-x)); }

DEVINL u64 ald64(const u64* p) {
    return __hip_atomic_load(p, __ATOMIC_RELAXED, __HIP_MEMORY_SCOPE_AGENT);
}
DEVINL unsigned ald32(const unsigned* p) {
    return __hip_atomic_load(p, __ATOMIC_RELAXED, __HIP_MEMORY_SCOPE_AGENT);
}
DEVINL void ast64(u64* p, u64 v) {
    __hip_atomic_store(p, v, __ATOMIC_RELAXED, __HIP_MEMORY_SCOPE_AGENT);
}
DEVINL void ast32u(unsigned* p, unsigned v) {
    __hip_atomic_store(p, v, __ATOMIC_RELAXED, __HIP_MEMORY_SCOPE_AGENT);
}

// ---------------------------------------------------------------------------
__global__ void prepass(const float* __restrict__ Wx0, const float* __restrict__ Wh0,
                        const float* __restrict__ Ws0,
                        const float* __restrict__ Wx1, const float* __restrict__ Wh1,
                        const float* __restrict__ Ws1,
                        const float* __restrict__ Wrx0, const float* __restrict__ Wrh0,
                        const float* __restrict__ Wrx1, const float* __restrict__ Wrh1,
                        unsigned char* __restrict__ ws)
{
    unsigned short* whT  = (unsigned short*)(ws + OFF_WH);
    unsigned short* wxT  = (unsigned short*)(ws + OFF_WX);
    unsigned short* wsT  = (unsigned short*)(ws + OFF_WS);
    unsigned short* wrxT = (unsigned short*)(ws + OFF_WRX);
    unsigned short* wrhT = (unsigned short*)(ws + OFF_WRH);
    int tid = blockIdx.x * blockDim.x + threadIdx.x;
    int NT  = gridDim.x * blockDim.x;
    for (int e = tid; e < 2*1024*256; e += NT) {
        int d = e >> 18, r = e & 262143, n = r >> 8, k = r & 255;
        whT[e] = f2bf((d ? Wh1 : Wh0)[k*1024 + n]);
        wxT[e] = f2bf((d ? Wx1 : Wx0)[k*1024 + n]);
        wsT[e] = f2bf((d ? Ws1 : Ws0)[k*1024 + n]);
    }
    for (int e = tid; e < 2*2*256*256; e += NT) {
        int d = e >> 17, r = e & 131071, kk = r >> 16, r2 = r & 65535;
        int j = r2 >> 8, k = r2 & 255;
        wrxT[e] = f2bf((d ? Wrx1 : Wrx0)[(kk*256 + k)*256 + j]);
        wrhT[e] = f2bf((d ? Wrh1 : Wrh0)[(kk*256 + k)*256 + j]);
    }
    if (blockIdx.x == 0 && threadIdx.x < 256) {
        unsigned* f = (unsigned*)ws;
#pragma unroll
        for (int i = 0; i < 4; ++i) f[threadIdx.x*4 + i] = 0u;
    }
}

// ---------------------------------------------------------------------------
// sA: u16[2 Mt][16 kt][4 lq][16 m][8].  kt 0..7 = h, 8..15 = s.
#define FRAG_U64(Mt,kt,lqv,m) \
    ((u64*)(sA + (size_t)(((((Mt)*16+(kt))*4+(lqv))*16+(m))*8)))

__launch_bounds__(256, 1)
__global__ void bislstm(const float* __restrict__ inputs, const float* __restrict__ mask,
                        const float* __restrict__ b0,  const float* __restrict__ b1,
                        const float* __restrict__ br0, const float* __restrict__ br1,
                        const int* __restrict__ idxp,
                        unsigned char* __restrict__ ws, float* __restrict__ out)
{
    const int bid = blockIdx.x;
    const int d   = bid >> 5;
    const int g   = bid & 31;
    const int tid = threadIdx.x;
    const int wave = tid >> 6, lane = tid & 63;
    const int lm = lane & 15, lq = lane >> 4;

    __shared__ __align__(16) unsigned short sA[16384];   // 32 KB frags
    __shared__ __align__(16) float cL[32][260];
    __shared__ __align__(16) unsigned short rL[32][264];
    __shared__ float zs[2][32][16];
    __shared__ float rsxS[2][32][16];
    __shared__ float rshS[32][16];
    __shared__ float sCex[32][8];
    __shared__ __align__(8) unsigned short sHb[256];
    __shared__ float mL[32];

    const unsigned short* whT  = (const unsigned short*)(ws + OFF_WH)  + (size_t)d*1024*256;
    const unsigned short* wxT  = (const unsigned short*)(ws + OFF_WX)  + (size_t)d*1024*256;
    const unsigned short* wsT  = (const unsigned short*)(ws + OFF_WS)  + (size_t)d*1024*256;
    const unsigned short* wrxT = (const unsigned short*)(ws + OFF_WRX) + (size_t)d*2*256*256;
    const unsigned short* wrhT = (const unsigned short*)(ws + OFF_WRH) + (size_t)d*2*256*256;
    u64* HbufU = (u64*)(ws + OFF_H);
    u64* CbufU = (u64*)(ws + OFF_C);
    u64* RbufU = (u64*)(ws + OFF_R);
    unsigned* flags = (unsigned*)ws + d*512;
    const int idxv = idxp[0];
    const float* bd  = d ? b1  : b0;
    const float* brd = d ? br1 : br0;

    const int zMt = wave & 1, zNt = wave >> 1;
    const int znl = zNt*16 + lm;
    const int zcol = (znl >> 3)*256 + g*8 + (znl & 7);
    const int rks = lm >> 3;
    const int rj  = g*8 + (lm & 7);

    bf16x8 whf[8], wsf[8], wxf[8], rwf[8], wbig[4][8];
#pragma unroll
    for (int kt = 0; kt < 8; ++kt) {
        whf[kt] = *(const bf16x8*)(whT + (size_t)zcol*256 + kt*32 + lq*8);
        wsf[kt] = *(const bf16x8*)(wsT + (size_t)zcol*256 + kt*32 + lq*8);
        wxf[kt] = *(const bf16x8*)(wxT + (size_t)zcol*256 + kt*32 + lq*8);
    }
    {
        const unsigned short* wrT = (wave < 2) ? wrhT : wrxT;
#pragma unroll
        for (int kt = 0; kt < 8; ++kt)
            rwf[kt] = *(const bf16x8*)(wrT + (size_t)(rks*256 + rj)*256 + kt*32 + lq*8);
    }
    float brj[16];
#pragma unroll
    for (int n = 0; n < 4; ++n) {
        const int j16 = wave*64 + n*16 + lm;
#pragma unroll
        for (int kt = 0; kt < 8; ++kt)
            wbig[n][kt] = *(const bf16x8*)(wrhT + (size_t)(idxv*256 + j16)*256 + kt*32 + lq*8);
#pragma unroll
        for (int r = 0; r < 4; ++r)
            brj[n*4 + r] = brd[idxv*256 + wave*64 + n*16 + lq*4 + r];
    }

    {
        u64* z8 = (u64*)sA;
#pragma unroll
        for (int i = 0; i < 16; ++i) z8[tid + 256*i] = 0ULL;
    }

    f32x4 zacc;
    {
        const int tx0 = d ? (Ss - 1) : 0;
        const float* xp = inputs + (((size_t)(zMt*16 + lm)*Ss + tx0) << 8) + lq*8;
        bf16x8 xf[8];
#pragma unroll
        for (int kt = 0; kt < 8; ++kt) {
            float4 v0 = *(const float4*)(xp + kt*32);
            float4 v1 = *(const float4*)(xp + kt*32 + 4);
            u64x2 pk; pk.x = pack4(v0); pk.y = pack4(v1);
            xf[kt] = __builtin_bit_cast(bf16x8, pk);
        }
        f32x4 a = {0.f, 0.f, 0.f, 0.f};
#pragma unroll
        for (int kt = 0; kt < 8; ++kt)
            a = __builtin_amdgcn_mfma_f32_16x16x32_bf16(xf[kt], wxf[kt], a, 0, 0, 0);
        zacc = a;
        if (wave >= 2) {
            f32x4 ra = {0.f, 0.f, 0.f, 0.f};
#pragma unroll
            for (int kt = 0; kt < 8; ++kt)
                ra = __builtin_amdgcn_mfma_f32_16x16x32_bf16(xf[kt], rwf[kt], ra, 0, 0, 0);
#pragma unroll
            for (int r = 0; r < 4; ++r) rsxS[0][zMt*16 + lq*4 + r][lm] = ra[r];
        }
    }
    __syncthreads();
    if (wave == 3) {   // publish rsx_0 (idx share), coalesced from LDS
        const int b_ = lane >> 1, hf_ = lane & 1;
        float4 f4;
        f4.x = rsxS[0][b_][idxv*8 + hf_*4 + 0];
        f4.y = rsxS[0][b_][idxv*8 + hf_*4 + 1];
        f4.z = rsxS[0][b_][idxv*8 + hf_*4 + 2];
        f4.w = rsxS[0][b_][idxv*8 + hf_*4 + 3];
        ast64(RbufU + (size_t)d*2048 + (size_t)b_*64 + g*2 + hf_, pack4(f4));
    }

    const int eb = tid >> 3, ej = tid & 7;
    const int gj = g*8 + ej;
    const float bias_i = bd[gj], bias_f = bd[256+gj], bias_g = bd[512+gj], bias_o = bd[768+gj];
    const float brr0 = brd[gj], brr1 = brd[256+gj];
    float hprev = 0.f, cprev = 0.f, s1prev = 0.f;
    float sreg[2][4][4] = {};

    const unsigned short* aBase = sA + (size_t)(zMt*8192 + lq*128 + lm*8);

#pragma unroll 1
    for (int t = 0; t < Ss; ++t) {
        const int tx = d ? (Ss - 1 - t) : t;
        const int pc = t & 1, pcn = pc ^ 1;
        const unsigned want = (unsigned)(t + 1);
        const bool more = (t + 1 < Ss);

        // ---- P1 ----
        if (tid < 32) mL[tid] = mask[(size_t)tid*Ss + tx];
        {
            f32x4 acc = zacc;
#pragma unroll
            for (int kt = 0; kt < 8; ++kt)
                acc = __builtin_amdgcn_mfma_f32_16x16x32_bf16(*(const bf16x8*)(aBase + kt*512), whf[kt], acc, 0, 0, 0);
#pragma unroll
            for (int kt = 0; kt < 8; ++kt)
                acc = __builtin_amdgcn_mfma_f32_16x16x32_bf16(*(const bf16x8*)(aBase + (8+kt)*512), wsf[kt], acc, 0, 0, 0);
#pragma unroll
            for (int r = 0; r < 4; ++r)
                zs[zNt][zMt*16 + lq*4 + r][lm] = acc[r];
        }
        __syncthreads();                                   // S1

        // ---- P2 ----
        float m_, cu_, hu_;
        {
            float zi = zs[0][eb][ej]   + bias_i;
            float zf = zs[0][eb][8+ej] + bias_f;
            float zg = zs[1][eb][ej]   + bias_g;
            float zo = zs[1][eb][8+ej] + bias_o;
            float cn = sigm(zf)*cprev + sigm(zi)*tanhf(zg);
            float hn = sigm(zo)*tanhf(cn);
            m_  = mL[eb];
            cu_ = m_*cn + (1.f - m_)*cprev;
            hu_ = m_*hn + (1.f - m_)*hprev;
            cprev = cu_; hprev = hu_;
            sHb[tid] = f2bf(hu_);
            sCex[eb][ej] = cu_;
        }
        __syncthreads();                                   // S2

        // ---- P2b: coalesced publish + ack ----
        if (wave == 0) {
            u64 pk = *(const u64*)&sHb[lane*4];
            ast64(HbufU + (size_t)(pc*2 + d)*2048 + (size_t)(lane>>1)*64 + g*2 + (lane&1), pk);
        } else if (wave == 1) {
            const int b_ = lane >> 1, hf_ = lane & 1;
            u64 p0 = *(const u64*)&sCex[b_][hf_*4];
            u64 p1 = *(const u64*)&sCex[b_][hf_*4 + 2];
            u64* cp = CbufU + (size_t)(pc*2 + d)*4096 + (size_t)b_*128 + g*4 + hf_*2;
            ast64(cp, p0); ast64(cp + 1, p1);
        }
        asm volatile("s_waitcnt vmcnt(0)" ::: "memory");
        __syncthreads();                                   // S3

        // ---- P3: flag ; out ; x'/zacc/rsx' ; wave0 poll ----
        if (tid == 0) ast32u(flags + g*16, want);
        out[((size_t)tx*32 + eb)*512 + d*256 + gj] = hu_;
        out[16777216 + ((size_t)tx*32 + eb)*512 + d*256 + gj] = cu_;
        if (more) {
            const int txn = d ? (Ss - 2 - t) : (t + 1);
            const float* xp = inputs + (((size_t)(zMt*16 + lm)*Ss + txn) << 8) + lq*8;
            bf16x8 xf[8];
#pragma unroll
            for (int kt = 0; kt < 8; ++kt) {
                float4 v0 = *(const float4*)(xp + kt*32);
                float4 v1 = *(const float4*)(xp + kt*32 + 4);
                u64x2 pk; pk.x = pack4(v0); pk.y = pack4(v1);
                xf[kt] = __builtin_bit_cast(bf16x8, pk);
            }
            f32x4 a = {0.f, 0.f, 0.f, 0.f};
#pragma unroll
            for (int kt = 0; kt < 8; ++kt)
                a = __builtin_amdgcn_mfma_f32_16x16x32_bf16(xf[kt], wxf[kt], a, 0, 0, 0);
            zacc = a;
            if (wave >= 2) {
                f32x4 ra = {0.f, 0.f, 0.f, 0.f};
#pragma unroll
                for (int kt = 0; kt < 8; ++kt)
                    ra = __builtin_amdgcn_mfma_f32_16x16x32_bf16(xf[kt], rwf[kt], ra, 0, 0, 0);
#pragma unroll
                for (int r = 0; r < 4; ++r) rsxS[pcn][zMt*16 + lq*4 + r][lm] = ra[r];
            }
        }
        if (wave == 0) {
            for (;;) {
                unsigned v = ald32(flags + (lane & 31)*16);
                if (__ballot(v < want) == 0ULL) break;
                __builtin_amdgcn_s_sleep(1);
            }
            asm volatile("" ::: "memory");
        }
        __syncthreads();                                   // S3b

        // ---- P4pre: coalesced gather -> LDS ----
        {
            const u64* Hs = (const u64*)(ws + OFF_H) + (size_t)(pc*2 + d)*2048;
#pragma unroll
            for (int i = 0; i < 4; ++i) {
                int b_ = (tid & 7) + 8*i;
                int jj = tid >> 3;
                u64 v0 = ald64(Hs + (size_t)b_*64 + jj*2);
                u64 v1 = ald64(Hs + (size_t)b_*64 + jj*2 + 1);
                u64x2 pk; pk.x = v0; pk.y = v1;
                *(u64x2*)FRAG_U64(b_ >> 4, jj >> 2, jj & 3, b_ & 15) = pk;
            }
            const u64* Cb = (const u64*)(ws + OFF_C) + (size_t)(pc*2 + d)*4096;
#pragma unroll
            for (int i = 0; i < 8; ++i) {
                int q = i*1024 + tid*4;
                int b_ = q >> 8, j = q & 255;
                u64x2 pk; pk.x = ald64(Cb + (q >> 1)); pk.y = ald64(Cb + (q >> 1) + 1);
                *(u64x2*)&cL[b_][j] = pk;
            }
            const u64* Rb = (const u64*)(ws + OFF_R) + (size_t)(pc*2 + d)*2048;
#pragma unroll
            for (int i = 0; i < 4; ++i) {
                int q = i*2048 + tid*8;
                int b_ = q >> 8, j = q & 255;
                u64x2 pk; pk.x = ald64(Rb + (q >> 2)); pk.y = ald64(Rb + (q >> 2) + 1);
                *(u64x2*)&rL[b_][j] = pk;
            }
        }
        __syncthreads();                                   // S4

        // ---- P4: wave3 publish rsx_{t+1} ; transposed replicated r GEMM ----
        if (wave == 3 && more) {
            const int b_ = lane >> 1, hf_ = lane & 1;
            float4 f4;
            f4.x = rsxS[pcn][b_][idxv*8 + hf_*4 + 0];
            f4.y = rsxS[pcn][b_][idxv*8 + hf_*4 + 1];
            f4.z = rsxS[pcn][b_][idxv*8 + hf_*4 + 2];
            f4.w = rsxS[pcn][b_][idxv*8 + hf_*4 + 3];
            ast64(RbufU + (size_t)(pcn*2 + d)*2048 + (size_t)b_*64 + g*2 + hf_, pack4(f4));
        }
#pragma unroll
        for (int Mt = 0; Mt < 2; ++Mt) {
            bf16x8 hfB[8];
#pragma unroll
            for (int kt = 0; kt < 8; ++kt)
                hfB[kt] = *(const bf16x8*)(sA + (size_t)(Mt*8192 + kt*512 + lq*128 + lm*8));
            if (wave < 2 && Mt == wave) {
                f32x4 ra = {0.f, 0.f, 0.f, 0.f};
#pragma unroll
                for (int kt = 0; kt < 8; ++kt)
                    ra = __builtin_amdgcn_mfma_f32_16x16x32_bf16(hfB[kt], rwf[kt], ra, 0, 0, 0);
#pragma unroll
                for (int r = 0; r < 4; ++r) rshS[wave*16 + lq*4 + r][lm] = ra[r];
            }
            const int bb = Mt*16 + lm;
            const float mv = mL[bb];
#pragma unroll
            for (int n = 0; n < 4; ++n) {
                f32x4 a = {0.f, 0.f, 0.f, 0.f};
#pragma unroll
                for (int kt = 0; kt < 8; ++kt)
                    a = __builtin_amdgcn_mfma_f32_16x16x32_bf16(wbig[n][kt], hfB[kt], a, 0, 0, 0);
                const int j0 = wave*64 + n*16 + lq*4;
                float4 cv4 = *(const float4*)&cL[bb][j0];
                u64 rv64 = *(const u64*)&rL[bb][j0];
                u64 pk = 0ULL;
                float4 o4;
#pragma unroll
                for (int r = 0; r < 4; ++r) {
                    float cv = (r == 0) ? cv4.x : (r == 1) ? cv4.y : (r == 2) ? cv4.z : cv4.w;
                    float rx = __builtin_bit_cast(float, ((unsigned)(unsigned short)(rv64 >> (r*16))) << 16);
                    float rr = sigm(a[r] + rx + brj[n*4 + r]);
                    float so = sreg[Mt][n][r];
                    float sn = rr*so + (1.f - rr)*cv;
                    float su = mv*sn + (1.f - mv)*so;
                    sreg[Mt][n][r] = su;
                    pk |= (u64)f2bf(su) << (r*16);
                    if (r == 0) o4.x = su; else if (r == 1) o4.y = su; else if (r == 2) o4.z = su; else o4.w = su;
                }
                const int ktp = 8 + (j0 >> 5);
                const int lqv = (j0 >> 3) & 3;
                const int half = (j0 >> 2) & 1;
                *(u64*)(sA + (size_t)((((Mt*16 + ktp)*4 + lqv)*16 + lm)*8 + half*4)) = pk;
                if ((j0 >> 3) == g)
                    *(float4*)(out + 33554432 + (((size_t)idxv*1024 + tx)*32 + bb)*512 + d*256 + j0) = o4;
            }
        }
        __syncthreads();                                   // S5

        // ---- P5: output-only share (1-idx) ----
        {
            const int k1 = 1 - idxv;
            float rv = rsxS[pc][eb][k1*8 + ej] + rshS[eb][k1*8 + ej] + (k1 ? brr1 : brr0);
            float rr = sigm(rv);
            float sn = rr*s1prev + (1.f - rr)*cu_;
            float su = m_*sn + (1.f - m_)*s1prev;
            s1prev = su;
            out[33554432 + (((size_t)k1*1024 + tx)*32 + eb)*512 + d*256 + gj] = su;
        }
    }
}

// ---------------------------------------------------------------------------
extern "C" void kernel_launch(void* const* d_in, const int* in_sizes, int n_in,
                              void* d_out, int out_size, void* d_ws, size_t ws_size,
                              hipStream_t stream) {
    const float* inputs = (const float*)d_in[0];
    const float* mask_  = (const float*)d_in[1];
    const float* Wx0  = (const float*)d_in[2];
    const float* Wh0  = (const float*)d_in[3];
    const float* Ws0  = (const float*)d_in[4];
    const float* b0   = (const float*)d_in[5];
    const float* Wrx0 = (const float*)d_in[6];
    const float* Wrh0 = (const float*)d_in[7];
    const float* br0  = (const float*)d_in[8];
    const float* Wx1  = (const float*)d_in[9];
    const float* Wh1  = (const float*)d_in[10];
    const float* Ws1  = (const float*)d_in[11];
    const float* b1   = (const float*)d_in[12];
    const float* Wrx1 = (const float*)d_in[13];
    const float* Wrh1 = (const float*)d_in[14];
    const float* br1  = (const float*)d_in[15];
    const int*   idxp = (const int*)d_in[16];
    unsigned char* ws = (unsigned char*)d_ws;

    hipLaunchKernelGGL(prepass, dim3(512), dim3(256), 0, stream,
                       Wx0, Wh0, Ws0, Wx1, Wh1, Ws1, Wrx0, Wrh0, Wrx1, Wrh1, ws);
    hipLaunchKernelGGL(bislstm, dim3(64), dim3(256), 0, stream,
                       inputs, mask_, b0, b1, br0, br1, idxp,
                       ws, (float*)d_out);
}